// Round 3
// baseline (148.953 us; speedup 1.0000x reference)
//
#include <hip/hip_runtime.h>
#include <hip/hip_bf16.h>

#define T_DIM 8192
#define H_DIM 2048
#define D_DIM 1024
#define PAD_R 32          // zero lead rows of xb = scan warm-up window
#define KT    16          // K tiles of BK=64

typedef __bf16 bf16x8 __attribute__((ext_vector_type(8)));
typedef float floatx4 __attribute__((ext_vector_type(4)));
typedef unsigned short u16;

__device__ __forceinline__ u16 f2bf(float f) {
    __hip_bfloat16 b = __float2bfloat16(f);
    return *reinterpret_cast<u16*>(&b);
}
__device__ __forceinline__ float bf2f(u16 v) {
    return __uint_as_float((unsigned)v << 16);
}

#define GLDS(g, l) \
    __builtin_amdgcn_global_load_lds((const __attribute__((address_space(1))) void*)(g), \
                                     (__attribute__((address_space(3))) void*)(l), 16, 0, 0)

// ---------------------------------------------------------------------------
// fp32 -> bf16 convert: xb gets 32 leading ZERO rows (scan warm-up), then x;
// bb = B. ~63MB traffic -> ~10us at BW.
// ---------------------------------------------------------------------------
__global__ __launch_bounds__(256) void conv_kernel(const float* __restrict__ x,
                                                   const float* __restrict__ Bm,
                                                   u16* __restrict__ xb,
                                                   u16* __restrict__ bb) {
    const int nPad4 = PAD_R * D_DIM / 4;
    const int nX4   = (T_DIM + PAD_R) * D_DIM / 4;
    const int nB4   = H_DIM * D_DIM / 4;
    int i = blockIdx.x * 256 + threadIdx.x;
    if (i < nX4) {
        ushort4 o;
        if (i < nPad4) {
            o.x = o.y = o.z = o.w = 0;
        } else {
            const float4 v = reinterpret_cast<const float4*>(x)[i - nPad4];
            o.x = f2bf(v.x); o.y = f2bf(v.y); o.z = f2bf(v.z); o.w = f2bf(v.w);
        }
        reinterpret_cast<ushort4*>(xb)[i] = o;
    } else {
        i -= nX4;
        if (i >= nB4) return;
        const float4 v = reinterpret_cast<const float4*>(Bm)[i];
        ushort4 o;
        o.x = f2bf(v.x); o.y = f2bf(v.y); o.z = f2bf(v.z); o.w = f2bf(v.w);
        reinterpret_cast<ushort4*>(bb)[i] = o;
    }
}

// ---------------------------------------------------------------------------
// Fused 288x256 GEMM + scan, DEEP-PIPELINED 8-phase / 2-K-tile iterations.
// 512 thr = 8 waves (2M x 4N), per-wave 144x64 (acc[9][4]), BK=64.
// Fixed buffer parity: even K-tiles -> buf0, odd -> buf1 (no swaps).
// Same-buffer restage: A(t) fully read after P3 -> A(t+2) staged P4/P5 into
// same buffer; B(t) read after P2 -> B(t+2) staged P3/P4. A(t+1) tail staged
// at P1 (head at prev P8). Counted waits: vmcnt(6) at end-P4 and end-P8
// (remaining = B-next 4 + A-next-head 2, identical for both wave classes);
// every staged load has >=4 phases (~2000cy) before its consumption -> no
// per-window drain stall (r2 waited on loads only 3 phases old = the stall).
// Granule-XOR swizzle (col ^= (row&7)*8) both sides -> 0 bank conflicts.
// LDS: A 2x36KB + B 2x32KB = 136KB staging, reused as u-tile [288][256] bf16
// for the in-block scan epilogue (2 half-scans of 32 warm + 128 out).
// ---------------------------------------------------------------------------
__device__ __forceinline__ bf16x8 lds_frag(const u16* base, int row, int kx, int kseg) {
    const int cp = (kx + kseg * 8) ^ ((row & 7) * 8);
    return *reinterpret_cast<const bf16x8*>(base + row * 64 + cp);
}

#define MFMA_Q(MI0, CNT, NH, BF)                                                     \
    _Pragma("unroll")                                                                \
    for (int kx = 0; kx < 2; ++kx)                                                   \
        _Pragma("unroll")                                                            \
        for (int mi = 0; mi < (CNT); ++mi)                                           \
            _Pragma("unroll")                                                        \
            for (int nj = 0; nj < 2; ++nj)                                           \
                acc[(MI0) + mi][(NH) * 2 + nj] =                                     \
                    __builtin_amdgcn_mfma_f32_16x16x32_bf16(                         \
                        af[mi][kx], BF[nj][kx], acc[(MI0) + mi][(NH) * 2 + nj],      \
                        0, 0, 0);

#define PH_BAR()  __builtin_amdgcn_s_barrier()
#define PH_LGKM() asm volatile("s_waitcnt lgkmcnt(0)" ::: "memory")

__global__ __launch_bounds__(512, 2) void gemm_kernel(const u16* __restrict__ xb,
                                                      const u16* __restrict__ bb,
                                                      const float* __restrict__ lam,
                                                      float* __restrict__ out) {
    __shared__ alignas(16) u16 smem[73728];   // 147456B; staging uses 69632 u16
    u16* sA = smem;                   // 2 bufs x 18432 u16 ([288][64])
    u16* sB = smem + 36864;           // 2 bufs x 16384 u16 ([256][64])

    const int tid  = threadIdx.x;
    const int lane = tid & 63;
    const int wid  = tid >> 6;
    const int lrow = lane & 15;
    const int kseg = lane >> 4;
    const int wm   = (wid >> 2) * 144;
    const int wn   = (wid & 3) * 64;

    // T1: XCD-aware mapping (bijective; 256 blocks, 8 XCDs).
    const int bid = blockIdx.x;
    const int xcd = bid & 7, idx = bid >> 3;
    const int bn  = (xcd & 1) * 4 + (idx & 3);
    const int bm  = (xcd >> 1) * 8 + (idx >> 2);

    // staging map: 512 thr * 16B = 64 rows/GLDS unit; row offsets 0 mod 8 ->
    // swizzle consistent with reader.
    const int rS = tid >> 3;
    const int cS = ((tid & 7) * 8) ^ ((rS & 7) * 8);
    const u16* gA = xb + (size_t)(bm * 256 + rS) * D_DIM + cS;  // padded space
    const u16* gB = bb + (size_t)(bn * 256 + rS) * D_DIM + cS;

    u16* A0 = sA;  u16* A1 = sA + 18432;
    u16* B0 = sB;  u16* B1 = sB + 16384;

    floatx4 acc[9][4] = {};
    bf16x8 af[5][2], b0[2][2], b1[2][2];

    // ---- prologue: A(0) full, B(0), B(1), A(1) head units {0,1}.
#pragma unroll
    for (int u = 0; u < 4; ++u)
        GLDS(gA + (size_t)(u * 64) * D_DIM, A0 + u * 4096 + tid * 8);
    if (tid < 256)
        GLDS(gA + (size_t)256 * D_DIM, A0 + 16384 + tid * 8);
#pragma unroll
    for (int u = 0; u < 4; ++u)
        GLDS(gB + (size_t)(u * 64) * D_DIM, B0 + u * 4096 + tid * 8);
#pragma unroll
    for (int u = 0; u < 4; ++u)
        GLDS(gB + (size_t)(u * 64) * D_DIM + 64, B1 + u * 4096 + tid * 8);
    GLDS(gA + 64, A1 + tid * 8);
    GLDS(gA + (size_t)64 * D_DIM + 64, A1 + 4096 + tid * 8);
    asm volatile("s_waitcnt vmcnt(6)" ::: "memory");
    PH_BAR();

#pragma unroll 1
    for (int i = 0; i < KT / 2; ++i) {
        const int t2 = 2 * i;
        const u16* ga1 = gA + (size_t)(t2 + 1) * 64;
        const u16* ga2 = gA + (size_t)(t2 + 2) * 64;
        const u16* ga3 = gA + (size_t)(t2 + 3) * 64;
        const u16* gb2 = gB + (size_t)(t2 + 2) * 64;
        const u16* gb3 = gB + (size_t)(t2 + 3) * 64;
        const bool pre = (i < KT / 2 - 1);

        // ======== P1: ds A(t)[0..4] + B(t)h0; stage A(t+1) tail {2,3,warm}
#pragma unroll
        for (int mi = 0; mi < 5; ++mi)
#pragma unroll
            for (int kx = 0; kx < 2; ++kx)
                af[mi][kx] = lds_frag(A0, wm + mi * 16 + lrow, kx * 32, kseg);
#pragma unroll
        for (int nj = 0; nj < 2; ++nj)
#pragma unroll
            for (int kx = 0; kx < 2; ++kx)
                b0[nj][kx] = lds_frag(B0, wn + nj * 16 + lrow, kx * 32, kseg);
        GLDS(ga1 + (size_t)128 * D_DIM, A1 + 8192 + tid * 8);
        GLDS(ga1 + (size_t)192 * D_DIM, A1 + 12288 + tid * 8);
        if (tid < 256)
            GLDS(ga1 + (size_t)256 * D_DIM, A1 + 16384 + tid * 8);
        PH_BAR(); PH_LGKM();
        __builtin_amdgcn_s_setprio(1);
        MFMA_Q(0, 5, 0, b0)
        __builtin_amdgcn_s_setprio(0);
        PH_BAR();

        // ======== P2: ds B(t)h1
#pragma unroll
        for (int nj = 0; nj < 2; ++nj)
#pragma unroll
            for (int kx = 0; kx < 2; ++kx)
                b1[nj][kx] = lds_frag(B0, wn + 32 + nj * 16 + lrow, kx * 32, kseg);
        PH_BAR(); PH_LGKM();
        __builtin_amdgcn_s_setprio(1);
        MFMA_Q(0, 5, 1, b1)
        __builtin_amdgcn_s_setprio(0);
        PH_BAR();

        // ======== P3: ds A(t)[5..8]; stage B(t+2) {0,1} (B(t) reads done @P2)
#pragma unroll
        for (int mi = 0; mi < 4; ++mi)
#pragma unroll
            for (int kx = 0; kx < 2; ++kx)
                af[mi][kx] = lds_frag(A0, wm + 80 + mi * 16 + lrow, kx * 32, kseg);
        if (pre) {
            GLDS(gb2, B0 + tid * 8);
            GLDS(gb2 + (size_t)64 * D_DIM, B0 + 4096 + tid * 8);
        }
        PH_BAR(); PH_LGKM();
        __builtin_amdgcn_s_setprio(1);
        MFMA_Q(5, 4, 0, b0)
        __builtin_amdgcn_s_setprio(0);
        PH_BAR();

        // ======== P4: stage B(t+2) {2,3} + A(t+2) {0,1}; vmcnt(6)
        if (pre) {
            GLDS(gb2 + (size_t)128 * D_DIM, B0 + 8192 + tid * 8);
            GLDS(gb2 + (size_t)192 * D_DIM, B0 + 12288 + tid * 8);
            GLDS(ga2, A0 + tid * 8);
            GLDS(ga2 + (size_t)64 * D_DIM, A0 + 4096 + tid * 8);
        }
        PH_BAR();
        __builtin_amdgcn_s_setprio(1);
        MFMA_Q(5, 4, 1, b1)
        __builtin_amdgcn_s_setprio(0);
        if (pre) asm volatile("s_waitcnt vmcnt(6)" ::: "memory");
        else     asm volatile("s_waitcnt vmcnt(0)" ::: "memory");
        PH_BAR();

        // ======== P5: ds A(t+1)[0..4] + B(t+1)h0; stage A(t+2) {2,3,warm}
#pragma unroll
        for (int mi = 0; mi < 5; ++mi)
#pragma unroll
            for (int kx = 0; kx < 2; ++kx)
                af[mi][kx] = lds_frag(A1, wm + mi * 16 + lrow, kx * 32, kseg);
#pragma unroll
        for (int nj = 0; nj < 2; ++nj)
#pragma unroll
            for (int kx = 0; kx < 2; ++kx)
                b0[nj][kx] = lds_frag(B1, wn + nj * 16 + lrow, kx * 32, kseg);
        if (pre) {
            GLDS(ga2 + (size_t)128 * D_DIM, A0 + 8192 + tid * 8);
            GLDS(ga2 + (size_t)192 * D_DIM, A0 + 12288 + tid * 8);
            if (tid < 256)
                GLDS(ga2 + (size_t)256 * D_DIM, A0 + 16384 + tid * 8);
        }
        PH_BAR(); PH_LGKM();
        __builtin_amdgcn_s_setprio(1);
        MFMA_Q(0, 5, 0, b0)
        __builtin_amdgcn_s_setprio(0);
        PH_BAR();

        // ======== P6: ds B(t+1)h1
#pragma unroll
        for (int nj = 0; nj < 2; ++nj)
#pragma unroll
            for (int kx = 0; kx < 2; ++kx)
                b1[nj][kx] = lds_frag(B1, wn + 32 + nj * 16 + lrow, kx * 32, kseg);
        PH_BAR(); PH_LGKM();
        __builtin_amdgcn_s_setprio(1);
        MFMA_Q(0, 5, 1, b1)
        __builtin_amdgcn_s_setprio(0);
        PH_BAR();

        // ======== P7: ds A(t+1)[5..8]; stage B(t+3) {0,1}
#pragma unroll
        for (int mi = 0; mi < 4; ++mi)
#pragma unroll
            for (int kx = 0; kx < 2; ++kx)
                af[mi][kx] = lds_frag(A1, wm + 80 + mi * 16 + lrow, kx * 32, kseg);
        if (pre) {
            GLDS(gb3, B1 + tid * 8);
            GLDS(gb3 + (size_t)64 * D_DIM, B1 + 4096 + tid * 8);
        }
        PH_BAR(); PH_LGKM();
        __builtin_amdgcn_s_setprio(1);
        MFMA_Q(5, 4, 0, b0)
        __builtin_amdgcn_s_setprio(0);
        PH_BAR();

        // ======== P8: stage B(t+3) {2,3} + A(t+3) {0,1}; vmcnt(6)
        if (pre) {
            GLDS(gb3 + (size_t)128 * D_DIM, B1 + 8192 + tid * 8);
            GLDS(gb3 + (size_t)192 * D_DIM, B1 + 12288 + tid * 8);
            GLDS(ga3, A1 + tid * 8);
            GLDS(ga3 + (size_t)64 * D_DIM, A1 + 4096 + tid * 8);
        }
        PH_BAR();
        __builtin_amdgcn_s_setprio(1);
        MFMA_Q(5, 4, 1, b1)
        __builtin_amdgcn_s_setprio(0);
        if (pre) asm volatile("s_waitcnt vmcnt(6)" ::: "memory");
        else     asm volatile("s_waitcnt vmcnt(0)" ::: "memory");
        PH_BAR();
    }

    // ---- epilogue 1: acc -> LDS u-tile [288][256] bf16, kseg-XOR col swizzle.
    u16* ut = smem;
#pragma unroll
    for (int mi = 0; mi < 9; ++mi)
#pragma unroll
        for (int nj = 0; nj < 4; ++nj) {
            const int col = wn + nj * 16 + lrow;
#pragma unroll
            for (int r = 0; r < 4; ++r) {
                const int row = wm + mi * 16 + kseg * 4 + r;
                ut[row * 256 + (col ^ (kseg * 16))] = f2bf(acc[mi][nj][r]);
            }
        }
    __syncthreads();

    // ---- epilogue 2: two parallel half-scans per column (32 warm + 128 out).
    {
        const int half = tid >> 8;          // 0 or 1
        const int c    = tid & 255;
        const float a  = 1.0f / (1.0f + __expf(-lam[bn * 256 + c]));
        float h = 0.0f;
        const int rb = half * 128;
#pragma unroll 8
        for (int q = 0; q < 32; ++q) {
            const int l = rb + q;
            h = fmaf(a, h, bf2f(ut[l * 256 + (c ^ (((l >> 2) & 3) * 16))]));
        }
        float* op = out + (size_t)(bm * 256 + rb) * H_DIM + bn * 256 + c;
#pragma unroll 8
        for (int q = 0; q < 128; ++q) {
            const int l = rb + 32 + q;
            h = fmaf(a, h, bf2f(ut[l * 256 + (c ^ (((l >> 2) & 3) * 16))]));
            op[(size_t)q * H_DIM] = h;
        }
    }
}

// ---------------------------------------------------------------------------
extern "C" void kernel_launch(void* const* d_in, const int* in_sizes, int n_in,
                              void* d_out, int out_size, void* d_ws, size_t ws_size,
                              hipStream_t stream) {
    const float* x   = (const float*)d_in[0];   // [T, D]
    const float* lam = (const float*)d_in[1];   // [H]
    const float* B   = (const float*)d_in[2];   // [H, D]
    float* out = (float*)d_out;                 // [T, H]

    // ws: xb [T+32][D] bf16 (16.9MB) + bb [H][D] bf16 (4.2MB) = 21MB.
    u16* xb = (u16*)d_ws;
    u16* bb = xb + (size_t)(T_DIM + PAD_R) * D_DIM;

    const int n4 = ((T_DIM + PAD_R) * D_DIM + H_DIM * D_DIM) / 4;
    conv_kernel<<<(n4 + 255) / 256, 256, 0, stream>>>(x, B, xb, bb);
    gemm_kernel<<<256, 512, 0, stream>>>(xb, bb, lam, out);
}

// Round 4
// 143.964 us; speedup vs baseline: 1.0347x; 1.0347x over previous
//
#include <hip/hip_runtime.h>
#include <hip/hip_bf16.h>

#define T_DIM 8192
#define H_DIM 2048
#define D_DIM 1024
#define PAD_R 32          // zero lead rows of xb = scan warm-up window
#define KT    16          // K tiles of BK=64
#define USTR  292         // u-tile col stride (u16): odd*4B -> bank-spread cols

typedef __bf16 bf16x8 __attribute__((ext_vector_type(8)));
typedef float floatx4 __attribute__((ext_vector_type(4)));
typedef unsigned short u16;

__device__ __forceinline__ u16 f2bf(float f) {
    __hip_bfloat16 b = __float2bfloat16(f);
    return *reinterpret_cast<u16*>(&b);
}
__device__ __forceinline__ float bf2f(u16 v) {
    return __uint_as_float((unsigned)v << 16);
}

#define GLDS(g, l) \
    __builtin_amdgcn_global_load_lds((const __attribute__((address_space(1))) void*)(g), \
                                     (__attribute__((address_space(3))) void*)(l), 16, 0, 0)

// ---------------------------------------------------------------------------
// fp32 -> bf16 convert: xb gets 32 leading ZERO rows (scan warm-up), then x;
// bb = B. ~63MB traffic -> ~10us at BW.
// ---------------------------------------------------------------------------
__global__ __launch_bounds__(256) void conv_kernel(const float* __restrict__ x,
                                                   const float* __restrict__ Bm,
                                                   u16* __restrict__ xb,
                                                   u16* __restrict__ bb) {
    const int nPad4 = PAD_R * D_DIM / 4;
    const int nX4   = (T_DIM + PAD_R) * D_DIM / 4;
    const int nB4   = H_DIM * D_DIM / 4;
    int i = blockIdx.x * 256 + threadIdx.x;
    if (i < nX4) {
        ushort4 o;
        if (i < nPad4) {
            o.x = o.y = o.z = o.w = 0;
        } else {
            const float4 v = reinterpret_cast<const float4*>(x)[i - nPad4];
            o.x = f2bf(v.x); o.y = f2bf(v.y); o.z = f2bf(v.z); o.w = f2bf(v.w);
        }
        reinterpret_cast<ushort4*>(xb)[i] = o;
    } else {
        i -= nX4;
        if (i >= nB4) return;
        const float4 v = reinterpret_cast<const float4*>(Bm)[i];
        ushort4 o;
        o.x = f2bf(v.x); o.y = f2bf(v.y); o.z = f2bf(v.z); o.w = f2bf(v.w);
        reinterpret_cast<ushort4*>(bb)[i] = o;
    }
}

// ---------------------------------------------------------------------------
// Fused 288x256 GEMM + scan. ONE barrier per phase (pre-MFMA barrier removed:
// per-wave lgkmcnt(0) before MFMA already makes reads complete before the
// end-phase barrier, so staging-after-last-read ordering holds; waves may now
// skew within a phase -> one wave's MFMA overlaps another's ds_reads, turning
// per-phase cost from sum(LDS,MFMA) into ~max). sched_barrier(0) after each
// lgkm stops hipcc hoisting reg-only MFMA past the wait (rule #18).
// Deep pipeline (fixed parity, same-buffer restage) + vmcnt(6) at P4/P8 kept.
// Epilogue: u-tile stored COLUMN-major [256][USTR] bf16 -> repack is 36
// ds_write_b64 (lane's 4 acc vals = 4 consecutive rows of one col), scan
// reads 40 ds_read_b64 per thread. Out write (64MB fp32) is the ~11us floor.
// ---------------------------------------------------------------------------
__device__ __forceinline__ bf16x8 lds_frag(const u16* base, int row, int kx, int kseg) {
    const int cp = (kx + kseg * 8) ^ ((row & 7) * 8);
    return *reinterpret_cast<const bf16x8*>(base + row * 64 + cp);
}

#define MFMA_Q(MI0, CNT, NH, BF)                                                     \
    _Pragma("unroll")                                                                \
    for (int kx = 0; kx < 2; ++kx)                                                   \
        _Pragma("unroll")                                                            \
        for (int mi = 0; mi < (CNT); ++mi)                                           \
            _Pragma("unroll")                                                        \
            for (int nj = 0; nj < 2; ++nj)                                           \
                acc[(MI0) + mi][(NH) * 2 + nj] =                                     \
                    __builtin_amdgcn_mfma_f32_16x16x32_bf16(                         \
                        af[mi][kx], BF[nj][kx], acc[(MI0) + mi][(NH) * 2 + nj],      \
                        0, 0, 0);

#define PH_BAR()   __builtin_amdgcn_s_barrier()
#define PH_LGKM()  do { asm volatile("s_waitcnt lgkmcnt(0)" ::: "memory"); \
                        __builtin_amdgcn_sched_barrier(0); } while (0)

__global__ __launch_bounds__(512, 2) void gemm_kernel(const u16* __restrict__ xb,
                                                      const u16* __restrict__ bb,
                                                      const float* __restrict__ lam,
                                                      float* __restrict__ out) {
    __shared__ alignas(16) u16 smem[74752];   // 149504B; staging uses 69632 u16
    u16* sA = smem;                   // 2 bufs x 18432 u16 ([288][64])
    u16* sB = smem + 36864;           // 2 bufs x 16384 u16 ([256][64])

    const int tid  = threadIdx.x;
    const int lane = tid & 63;
    const int wid  = tid >> 6;
    const int lrow = lane & 15;
    const int kseg = lane >> 4;
    const int wm   = (wid >> 2) * 144;
    const int wn   = (wid & 3) * 64;

    // T1: XCD-aware mapping (bijective; 256 blocks, 8 XCDs).
    const int bid = blockIdx.x;
    const int xcd = bid & 7, idx = bid >> 3;
    const int bn  = (xcd & 1) * 4 + (idx & 3);
    const int bm  = (xcd >> 1) * 8 + (idx >> 2);

    // staging map: 512 thr * 16B = 64 rows/GLDS unit; row offsets 0 mod 8 ->
    // swizzle consistent with reader.
    const int rS = tid >> 3;
    const int cS = ((tid & 7) * 8) ^ ((rS & 7) * 8);
    const u16* gA = xb + (size_t)(bm * 256 + rS) * D_DIM + cS;  // padded space
    const u16* gB = bb + (size_t)(bn * 256 + rS) * D_DIM + cS;

    u16* A0 = sA;  u16* A1 = sA + 18432;
    u16* B0 = sB;  u16* B1 = sB + 16384;

    floatx4 acc[9][4] = {};
    bf16x8 af[5][2], b0[2][2], b1[2][2];

    // ---- prologue: A(0) full, B(0), B(1), A(1) head units {0,1}.
#pragma unroll
    for (int u = 0; u < 4; ++u)
        GLDS(gA + (size_t)(u * 64) * D_DIM, A0 + u * 4096 + tid * 8);
    if (tid < 256)
        GLDS(gA + (size_t)256 * D_DIM, A0 + 16384 + tid * 8);
#pragma unroll
    for (int u = 0; u < 4; ++u)
        GLDS(gB + (size_t)(u * 64) * D_DIM, B0 + u * 4096 + tid * 8);
#pragma unroll
    for (int u = 0; u < 4; ++u)
        GLDS(gB + (size_t)(u * 64) * D_DIM + 64, B1 + u * 4096 + tid * 8);
    GLDS(gA + 64, A1 + tid * 8);
    GLDS(gA + (size_t)64 * D_DIM + 64, A1 + 4096 + tid * 8);
    asm volatile("s_waitcnt vmcnt(6)" ::: "memory");
    PH_BAR();

#pragma unroll 1
    for (int i = 0; i < KT / 2; ++i) {
        const int t2 = 2 * i;
        const u16* ga1 = gA + (size_t)(t2 + 1) * 64;
        const u16* ga2 = gA + (size_t)(t2 + 2) * 64;
        const u16* ga3 = gA + (size_t)(t2 + 3) * 64;
        const u16* gb2 = gB + (size_t)(t2 + 2) * 64;
        const u16* gb3 = gB + (size_t)(t2 + 3) * 64;
        const bool pre = (i < KT / 2 - 1);

        // ======== P1: ds A(t)[0..4] + B(t)h0; stage A(t+1) tail {2,3,warm}
#pragma unroll
        for (int mi = 0; mi < 5; ++mi)
#pragma unroll
            for (int kx = 0; kx < 2; ++kx)
                af[mi][kx] = lds_frag(A0, wm + mi * 16 + lrow, kx * 32, kseg);
#pragma unroll
        for (int nj = 0; nj < 2; ++nj)
#pragma unroll
            for (int kx = 0; kx < 2; ++kx)
                b0[nj][kx] = lds_frag(B0, wn + nj * 16 + lrow, kx * 32, kseg);
        GLDS(ga1 + (size_t)128 * D_DIM, A1 + 8192 + tid * 8);
        GLDS(ga1 + (size_t)192 * D_DIM, A1 + 12288 + tid * 8);
        if (tid < 256)
            GLDS(ga1 + (size_t)256 * D_DIM, A1 + 16384 + tid * 8);
        PH_LGKM();
        __builtin_amdgcn_s_setprio(1);
        MFMA_Q(0, 5, 0, b0)
        __builtin_amdgcn_s_setprio(0);
        PH_BAR();

        // ======== P2: ds B(t)h1
#pragma unroll
        for (int nj = 0; nj < 2; ++nj)
#pragma unroll
            for (int kx = 0; kx < 2; ++kx)
                b1[nj][kx] = lds_frag(B0, wn + 32 + nj * 16 + lrow, kx * 32, kseg);
        PH_LGKM();
        __builtin_amdgcn_s_setprio(1);
        MFMA_Q(0, 5, 1, b1)
        __builtin_amdgcn_s_setprio(0);
        PH_BAR();

        // ======== P3: ds A(t)[5..8]; stage B(t+2) {0,1} (B(t) reads done @P2)
#pragma unroll
        for (int mi = 0; mi < 4; ++mi)
#pragma unroll
            for (int kx = 0; kx < 2; ++kx)
                af[mi][kx] = lds_frag(A0, wm + 80 + mi * 16 + lrow, kx * 32, kseg);
        if (pre) {
            GLDS(gb2, B0 + tid * 8);
            GLDS(gb2 + (size_t)64 * D_DIM, B0 + 4096 + tid * 8);
        }
        PH_LGKM();
        __builtin_amdgcn_s_setprio(1);
        MFMA_Q(5, 4, 0, b0)
        __builtin_amdgcn_s_setprio(0);
        PH_BAR();

        // ======== P4: stage B(t+2) {2,3} + A(t+2) {0,1}; vmcnt(6)
        if (pre) {
            GLDS(gb2 + (size_t)128 * D_DIM, B0 + 8192 + tid * 8);
            GLDS(gb2 + (size_t)192 * D_DIM, B0 + 12288 + tid * 8);
            GLDS(ga2, A0 + tid * 8);
            GLDS(ga2 + (size_t)64 * D_DIM, A0 + 4096 + tid * 8);
        }
        __builtin_amdgcn_s_setprio(1);
        MFMA_Q(5, 4, 1, b1)
        __builtin_amdgcn_s_setprio(0);
        if (pre) asm volatile("s_waitcnt vmcnt(6)" ::: "memory");
        else     asm volatile("s_waitcnt vmcnt(0)" ::: "memory");
        PH_BAR();

        // ======== P5: ds A(t+1)[0..4] + B(t+1)h0; stage A(t+2) {2,3,warm}
#pragma unroll
        for (int mi = 0; mi < 5; ++mi)
#pragma unroll
            for (int kx = 0; kx < 2; ++kx)
                af[mi][kx] = lds_frag(A1, wm + mi * 16 + lrow, kx * 32, kseg);
#pragma unroll
        for (int nj = 0; nj < 2; ++nj)
#pragma unroll
            for (int kx = 0; kx < 2; ++kx)
                b0[nj][kx] = lds_frag(B1, wn + nj * 16 + lrow, kx * 32, kseg);
        if (pre) {
            GLDS(ga2 + (size_t)128 * D_DIM, A0 + 8192 + tid * 8);
            GLDS(ga2 + (size_t)192 * D_DIM, A0 + 12288 + tid * 8);
            if (tid < 256)
                GLDS(ga2 + (size_t)256 * D_DIM, A0 + 16384 + tid * 8);
        }
        PH_LGKM();
        __builtin_amdgcn_s_setprio(1);
        MFMA_Q(0, 5, 0, b0)
        __builtin_amdgcn_s_setprio(0);
        PH_BAR();

        // ======== P6: ds B(t+1)h1
#pragma unroll
        for (int nj = 0; nj < 2; ++nj)
#pragma unroll
            for (int kx = 0; kx < 2; ++kx)
                b1[nj][kx] = lds_frag(B1, wn + 32 + nj * 16 + lrow, kx * 32, kseg);
        PH_LGKM();
        __builtin_amdgcn_s_setprio(1);
        MFMA_Q(0, 5, 1, b1)
        __builtin_amdgcn_s_setprio(0);
        PH_BAR();

        // ======== P7: ds A(t+1)[5..8]; stage B(t+3) {0,1}
#pragma unroll
        for (int mi = 0; mi < 4; ++mi)
#pragma unroll
            for (int kx = 0; kx < 2; ++kx)
                af[mi][kx] = lds_frag(A1, wm + 80 + mi * 16 + lrow, kx * 32, kseg);
        if (pre) {
            GLDS(gb3, B1 + tid * 8);
            GLDS(gb3 + (size_t)64 * D_DIM, B1 + 4096 + tid * 8);
        }
        PH_LGKM();
        __builtin_amdgcn_s_setprio(1);
        MFMA_Q(5, 4, 0, b0)
        __builtin_amdgcn_s_setprio(0);
        PH_BAR();

        // ======== P8: stage B(t+3) {2,3} + A(t+3) {0,1}; vmcnt(6)
        if (pre) {
            GLDS(gb3 + (size_t)128 * D_DIM, B1 + 8192 + tid * 8);
            GLDS(gb3 + (size_t)192 * D_DIM, B1 + 12288 + tid * 8);
            GLDS(ga3, A1 + tid * 8);
            GLDS(ga3 + (size_t)64 * D_DIM, A1 + 4096 + tid * 8);
        }
        __builtin_amdgcn_s_setprio(1);
        MFMA_Q(5, 4, 1, b1)
        __builtin_amdgcn_s_setprio(0);
        if (pre) asm volatile("s_waitcnt vmcnt(6)" ::: "memory");
        else     asm volatile("s_waitcnt vmcnt(0)" ::: "memory");
        PH_BAR();
    }

    // ---- epilogue 1: acc -> LDS u-tile, COLUMN-major [256][USTR] bf16.
    // Lane's 4 acc values (rows r0..r0+3 of one col) -> one ds_write_b64.
    u16* ut = smem;
#pragma unroll
    for (int mi = 0; mi < 9; ++mi)
#pragma unroll
        for (int nj = 0; nj < 4; ++nj) {
            const int col  = wn + nj * 16 + lrow;
            const int row0 = wm + mi * 16 + kseg * 4;
            ushort4 w;
            w.x = f2bf(acc[mi][nj][0]); w.y = f2bf(acc[mi][nj][1]);
            w.z = f2bf(acc[mi][nj][2]); w.w = f2bf(acc[mi][nj][3]);
            *reinterpret_cast<ushort4*>(ut + col * USTR + row0) = w;
        }
    __syncthreads();

    // ---- epilogue 2: two parallel half-scans per column (32 warm + 128 out),
    // ds_read_b64 (4 rows per read), coalesced fp32 stores.
    {
        const int half = tid >> 8;          // 0 or 1
        const int c    = tid & 255;
        const float a  = 1.0f / (1.0f + __expf(-lam[bn * 256 + c]));
        const u16* colp = ut + c * USTR;
        const int rb = half * 128;
        float h = 0.0f;
#pragma unroll
        for (int qb = 0; qb < 8; ++qb) {
            const ushort4 v = *reinterpret_cast<const ushort4*>(colp + rb + qb * 4);
            h = fmaf(a, h, bf2f(v.x)); h = fmaf(a, h, bf2f(v.y));
            h = fmaf(a, h, bf2f(v.z)); h = fmaf(a, h, bf2f(v.w));
        }
        float* op = out + (size_t)(bm * 256 + rb) * H_DIM + bn * 256 + c;
#pragma unroll 8
        for (int qb = 0; qb < 32; ++qb) {
            const ushort4 v = *reinterpret_cast<const ushort4*>(colp + rb + 32 + qb * 4);
            h = fmaf(a, h, bf2f(v.x)); op[(size_t)(qb * 4 + 0) * H_DIM] = h;
            h = fmaf(a, h, bf2f(v.y)); op[(size_t)(qb * 4 + 1) * H_DIM] = h;
            h = fmaf(a, h, bf2f(v.z)); op[(size_t)(qb * 4 + 2) * H_DIM] = h;
            h = fmaf(a, h, bf2f(v.w)); op[(size_t)(qb * 4 + 3) * H_DIM] = h;
        }
    }
}

// ---------------------------------------------------------------------------
extern "C" void kernel_launch(void* const* d_in, const int* in_sizes, int n_in,
                              void* d_out, int out_size, void* d_ws, size_t ws_size,
                              hipStream_t stream) {
    const float* x   = (const float*)d_in[0];   // [T, D]
    const float* lam = (const float*)d_in[1];   // [H]
    const float* B   = (const float*)d_in[2];   // [H, D]
    float* out = (float*)d_out;                 // [T, H]

    // ws: xb [T+32][D] bf16 (16.9MB) + bb [H][D] bf16 (4.2MB) = 21MB.
    u16* xb = (u16*)d_ws;
    u16* bb = xb + (size_t)(T_DIM + PAD_R) * D_DIM;

    const int n4 = ((T_DIM + PAD_R) * D_DIM + H_DIM * D_DIM) / 4;
    conv_kernel<<<(n4 + 255) / 256, 256, 0, stream>>>(x, B, xb, bb);
    gemm_kernel<<<256, 512, 0, stream>>>(xb, bb, lam, out);
}